// Round 1
// baseline (3279.415 us; speedup 1.0000x reference)
//
#include <hip/hip_runtime.h>

// Problem constants (hardcoded in the reference module)
#define P 4
#define NN 100000
#define MM 50000
#define EE 400000
#define DD 128

#define ROWS 32          // dst rows per block in fused kernel
#define ASTRIDE 260      // 256 + 4 pad: breaks LDS bank aliasing for stride-256 rows

// ---------------------------------------------------------------------------
// K1: per-(s,d)-pair degree count.  i indexes [16][E] flattened.
__global__ __launch_bounds__(256) void k_degree(const int* __restrict__ edge_dst,
                                                int* __restrict__ deg) {
    int i = blockIdx.x * 256 + threadIdx.x;
    if (i >= P * P * EE) return;
    int pair = i / EE;
    int d = edge_dst[i];
    atomicAdd(&deg[pair * MM + d], 1);
}

// ---------------------------------------------------------------------------
// K2: exclusive prefix sum of deg -> row_start, one block per pair.
__global__ __launch_bounds__(1024) void k_scan(const int* __restrict__ deg,
                                               int* __restrict__ row_start) {
    int pair = blockIdx.x;
    const int* dp = deg + pair * MM;
    int* rs = row_start + pair * (MM + 1);
    __shared__ int sh[1024];
    int running = 0;
    for (int base = 0; base < MM; base += 1024) {
        int i = base + (int)threadIdx.x;
        int v = (i < MM) ? dp[i] : 0;
        sh[threadIdx.x] = v;
        __syncthreads();
        for (int off = 1; off < 1024; off <<= 1) {
            int t = (threadIdx.x >= (unsigned)off) ? sh[threadIdx.x - off] : 0;
            __syncthreads();
            sh[threadIdx.x] += t;
            __syncthreads();
        }
        int incl = sh[threadIdx.x];
        if (i < MM) rs[i] = running + incl - v;   // exclusive
        running += sh[1023];
        __syncthreads();
    }
    if (threadIdx.x == 0) rs[MM] = running;       // == EE
}

// ---------------------------------------------------------------------------
// K3: counting-sort edges into CSR (src ids grouped by dst).
__global__ __launch_bounds__(256) void k_fill(const int* __restrict__ edge_src,
                                              const int* __restrict__ edge_dst,
                                              const int* __restrict__ row_start,
                                              int* __restrict__ cursor,
                                              int* __restrict__ csr) {
    int i = blockIdx.x * 256 + threadIdx.x;
    if (i >= P * P * EE) return;
    int pair = i / EE;
    int d = edge_dst[i];
    int pos = row_start[pair * (MM + 1) + d] + atomicAdd(&cursor[pair * MM + d], 1);
    csr[pair * EE + pos] = edge_src[i];
}

// ---------------------------------------------------------------------------
// K4: fused per-pair SAGE: gather-mean into LDS + [32x256]@[256x128] GEMM
//     + bias + (direct store | atomic scatter-merge).
// diagmode=1: blockIdx.y = d = s, plain float4 stores (initializes d_out).
// diagmode=0: blockIdx.y in [0,12) enumerates (s,d), s != d, atomicAdd merge.
__global__ __launch_bounds__(256) void k_sage(const float* __restrict__ x_all,
                                              const float* __restrict__ Ws_all,
                                              const float* __restrict__ Wn_all,
                                              const float* __restrict__ b_all,
                                              const int* __restrict__ row_start_all,
                                              const int* __restrict__ csr_all,
                                              const int* __restrict__ merge_all,
                                              float* __restrict__ out,
                                              int diagmode) {
    int y = blockIdx.y;
    int s, d;
    if (diagmode) { s = y; d = y; }
    else { d = y / 3; int r = y % 3; s = r + (r >= d ? 1 : 0); }
    int pair = s * P + d;

    const float* x   = x_all + (size_t)s * NN * DD;
    const float* Ws  = Ws_all + (size_t)s * DD * DD;
    const float* Wn  = Wn_all + (size_t)s * DD * DD;
    const float* bia = b_all + (size_t)s * DD;
    const int* row_start = row_start_all + (size_t)pair * (MM + 1);
    const int* csr       = csr_all + (size_t)pair * EE;
    const int* merge     = merge_all + (size_t)pair * MM;
    float* outd          = out + (size_t)d * MM * DD;

    __shared__ float A[ROWS * ASTRIDE];   // [32 rows][256 K] padded

    int m0 = blockIdx.x * ROWS;
    int tid = threadIdx.x;

    // stage x tile into A[:, 0:128] (float4, coalesced)
    for (int f = tid; f < ROWS * 32; f += 256) {
        int r = f >> 5, c4 = (f & 31) << 2;
        int m = m0 + r;
        float4 v = make_float4(0.f, 0.f, 0.f, 0.f);
        if (m < MM) v = *(const float4*)(x + (size_t)m * DD + c4);
        *(float4*)(A + r * ASTRIDE + c4) = v;
    }

    // gather-mean: wave w handles rows w*8 .. w*8+7; lane covers cols {l, l+64}
    int lane = tid & 63, wv = tid >> 6;
    for (int r0 = 0; r0 < 8; ++r0) {
        int r = wv * 8 + r0;
        int m = m0 + r;
        float a0 = 0.f, a1 = 0.f;
        if (m < MM) {
            int e0 = row_start[m], e1 = row_start[m + 1];
            for (int e = e0; e < e1; ++e) {
                int src = csr[e];                       // wave-uniform
                const float* xp = x + (size_t)src * DD;
                a0 += xp[lane];
                a1 += xp[lane + 64];
            }
            float inv = 1.0f / fmaxf((float)(e1 - e0), 1.0f);
            a0 *= inv; a1 *= inv;
        }
        A[r * ASTRIDE + 128 + lane] = a0;
        A[r * ASTRIDE + 192 + lane] = a1;
    }
    __syncthreads();

    // GEMM: out[32][128] = A[32][256] @ [Ws;Wn][256][128]
    // thread (rg, cg): rows rg*4..rg*4+3, cols cg*4..cg*4+3
    int cg = tid & 31, rg = tid >> 5;
    float4 acc[4];
    acc[0] = acc[1] = acc[2] = acc[3] = make_float4(0.f, 0.f, 0.f, 0.f);
    #pragma unroll
    for (int half = 0; half < 2; ++half) {
        const float* B = half ? Wn : Ws;
        int aoff = half << 7;
        for (int k = 0; k < 128; k += 4) {
            float4 b0 = *(const float4*)(B + (size_t)(k + 0) * DD + cg * 4);
            float4 b1 = *(const float4*)(B + (size_t)(k + 1) * DD + cg * 4);
            float4 b2 = *(const float4*)(B + (size_t)(k + 2) * DD + cg * 4);
            float4 b3 = *(const float4*)(B + (size_t)(k + 3) * DD + cg * 4);
            #pragma unroll
            for (int i = 0; i < 4; ++i) {
                float4 a = *(const float4*)(A + (rg * 4 + i) * ASTRIDE + aoff + k);
                acc[i].x += a.x * b0.x + a.y * b1.x + a.z * b2.x + a.w * b3.x;
                acc[i].y += a.x * b0.y + a.y * b1.y + a.z * b2.y + a.w * b3.y;
                acc[i].z += a.x * b0.z + a.y * b1.z + a.z * b2.z + a.w * b3.z;
                acc[i].w += a.x * b0.w + a.y * b1.w + a.z * b2.w + a.w * b3.w;
            }
        }
    }

    float4 bb = *(const float4*)(bia + cg * 4);
    #pragma unroll
    for (int i = 0; i < 4; ++i) {
        int m = m0 + rg * 4 + i;
        if (m >= MM) continue;
        float4 v = make_float4(acc[i].x + bb.x, acc[i].y + bb.y,
                               acc[i].z + bb.z, acc[i].w + bb.w);
        if (diagmode) {
            *(float4*)(outd + (size_t)m * DD + cg * 4) = v;
        } else {
            int om = merge[m];
            float* op = outd + (size_t)om * DD + cg * 4;
            atomicAdd(op + 0, v.x);
            atomicAdd(op + 1, v.y);
            atomicAdd(op + 2, v.z);
            atomicAdd(op + 3, v.w);
        }
    }
}

// ---------------------------------------------------------------------------
extern "C" void kernel_launch(void* const* d_in, const int* in_sizes, int n_in,
                              void* d_out, int out_size, void* d_ws, size_t ws_size,
                              hipStream_t stream) {
    const float* x     = (const float*)d_in[0];   // [P][N][D]
    const float* Ws    = (const float*)d_in[1];   // [P][D][D]
    const float* Wn    = (const float*)d_in[2];   // [P][D][D]
    const float* b     = (const float*)d_in[3];   // [P][D]
    const int*   esrc  = (const int*)d_in[4];     // [P][P][E]
    const int*   edst  = (const int*)d_in[5];     // [P][P][E]
    const int*   merge = (const int*)d_in[6];     // [P][P][M]
    float* out = (float*)d_out;                   // [P][M][D]

    // workspace layout (ints): deg[16*M] | cursor[16*M] | row_start[16*(M+1)] | csr[16*E]
    int* deg       = (int*)d_ws;
    int* cursor    = deg + 16 * MM;
    int* row_start = cursor + 16 * MM;
    int* csr       = row_start + 16 * (MM + 1);
    // total ≈ 35.2 MB

    hipMemsetAsync(deg, 0, sizeof(int) * (size_t)16 * MM * 2, stream);  // deg + cursor

    int eblocks = (P * P * EE + 255) / 256;    // 25000
    k_degree<<<eblocks, 256, 0, stream>>>(edst, deg);
    k_scan<<<16, 1024, 0, stream>>>(deg, row_start);
    k_fill<<<eblocks, 256, 0, stream>>>(esrc, edst, row_start, cursor, csr);

    int mblocks = (MM + ROWS - 1) / ROWS;      // 1563
    dim3 gdiag(mblocks, P);                    // (d,d) pairs: direct stores init d_out
    k_sage<<<gdiag, 256, 0, stream>>>(x, Ws, Wn, b, row_start, csr, merge, out, 1);
    dim3 goff(mblocks, P * P - P);             // 12 off-diagonal pairs: atomic merge
    k_sage<<<goff, 256, 0, stream>>>(x, Ws, Wn, b, row_start, csr, merge, out, 0);
}

// Round 2
// 2976.624 us; speedup vs baseline: 1.1017x; 1.1017x over previous
//
#include <hip/hip_runtime.h>

// Problem constants (hardcoded in the reference module)
#define P 4
#define NN 100000
#define MM 50000
#define EE 400000
#define DD 128
#define ROWS 32

// ---------------------------------------------------------------------------
// K1: per-(s,d) pair: count original-dst degree (for mean weights) AND
//     merged-dst counts (CSR row sizes). pair = s*P+d, i flattens [16][E].
__global__ __launch_bounds__(256) void k_count(const int* __restrict__ edge_dst,
                                               const int* __restrict__ merge,
                                               int* __restrict__ deg_orig,
                                               int* __restrict__ cnt_n) {
    int i = blockIdx.x * 256 + threadIdx.x;
    if (i >= P * P * EE) return;
    int pair = i / EE;
    int s = pair >> 2, d = pair & 3;
    int od = edge_dst[i];
    atomicAdd(&deg_orig[pair * MM + od], 1);
    int m = (s == d) ? od : merge[pair * MM + od];
    atomicAdd(&cnt_n[pair * MM + m], 1);
}

// K1b: self-term counts: inverse-merge list sizes (identity when s==d).
__global__ __launch_bounds__(256) void k_count_self(const int* __restrict__ merge,
                                                    int* __restrict__ cnt_s) {
    int i = blockIdx.x * 256 + threadIdx.x;
    if (i >= P * P * MM) return;
    int pair = i / MM;
    int r = i - pair * MM;
    int s = pair >> 2, d = pair & 3;
    int m = (s == d) ? r : merge[i];
    atomicAdd(&cnt_s[pair * MM + m], 1);
}

// ---------------------------------------------------------------------------
// K2: exclusive scan of cnt -> row_start; then zero cnt so it can be reused
//     as the fill cursor. blocks 0..15: neigh, 16..31: self.
__global__ __launch_bounds__(1024) void k_scan(int* __restrict__ cnt_n,
                                               int* __restrict__ rs_n,
                                               int* __restrict__ cnt_s,
                                               int* __restrict__ rs_s) {
    int which = blockIdx.x >> 4;
    int pair = blockIdx.x & 15;
    int* cnt = (which ? cnt_s : cnt_n) + pair * MM;
    int* rs  = (which ? rs_s : rs_n) + pair * (MM + 1);
    __shared__ int sh[1024];
    int running = 0;
    for (int base = 0; base < MM; base += 1024) {
        int i = base + (int)threadIdx.x;
        int v = (i < MM) ? cnt[i] : 0;
        sh[threadIdx.x] = v;
        __syncthreads();
        for (int off = 1; off < 1024; off <<= 1) {
            int t = (threadIdx.x >= (unsigned)off) ? sh[threadIdx.x - off] : 0;
            __syncthreads();
            sh[threadIdx.x] += t;
            __syncthreads();
        }
        int incl = sh[threadIdx.x];
        if (i < MM) rs[i] = running + incl - v;   // exclusive
        running += sh[1023];
        __syncthreads();
    }
    if (threadIdx.x == 0) rs[MM] = running;
    __syncthreads();
    for (int i = threadIdx.x; i < MM; i += 1024) cnt[i] = 0;   // reuse as cursor
}

// ---------------------------------------------------------------------------
// K3: counting-sort neigh edges into merged-dst CSR with mean weights.
__global__ __launch_bounds__(256) void k_fill(const int* __restrict__ edge_src,
                                              const int* __restrict__ edge_dst,
                                              const int* __restrict__ merge,
                                              const int* __restrict__ deg_orig,
                                              const int* __restrict__ rs_n,
                                              int* __restrict__ cur_n,
                                              int* __restrict__ csn_src,
                                              float* __restrict__ csn_w) {
    int i = blockIdx.x * 256 + threadIdx.x;
    if (i >= P * P * EE) return;
    int pair = i / EE;
    int s = pair >> 2, d = pair & 3;
    int od = edge_dst[i];
    int m = (s == d) ? od : merge[pair * MM + od];
    float w = 1.0f / fmaxf((float)deg_orig[pair * MM + od], 1.0f);
    int pos = rs_n[pair * (MM + 1) + m] + atomicAdd(&cur_n[pair * MM + m], 1);
    csn_src[pair * EE + pos] = edge_src[i];
    csn_w[pair * EE + pos] = w;
}

// K3b: self-term CSR (row r of x[s][:M] contributes to merged row m).
__global__ __launch_bounds__(256) void k_fill_self(const int* __restrict__ merge,
                                                   const int* __restrict__ rs_s,
                                                   int* __restrict__ cur_s,
                                                   int* __restrict__ css) {
    int i = blockIdx.x * 256 + threadIdx.x;
    if (i >= P * P * MM) return;
    int pair = i / MM;
    int r = i - pair * MM;
    int s = pair >> 2, d = pair & 3;
    int m = (s == d) ? r : merge[i];
    int pos = rs_s[pair * (MM + 1) + m] + atomicAdd(&cur_s[pair * MM + m], 1);
    css[pair * MM + pos] = r;
}

// ---------------------------------------------------------------------------
// K4: fully fused per-d kernel. For a 32-row output tile, loop s=0..3:
//     gather self-sum (K cols 0:128) + weighted neigh-sum (cols 128:256)
//     into LDS, then GEMM-accumulate against [Ws[s]; Wn[s]] + cnt*b[s].
//     Output written exactly once — no atomics.
__global__ __launch_bounds__(256, 4) void k_fused(const float* __restrict__ x_all,
                                                  const float* __restrict__ Ws_all,
                                                  const float* __restrict__ Wn_all,
                                                  const float* __restrict__ b_all,
                                                  const int* __restrict__ rs_n_all,
                                                  const int* __restrict__ csn_src_all,
                                                  const float* __restrict__ csn_w_all,
                                                  const int* __restrict__ rs_s_all,
                                                  const int* __restrict__ css_all,
                                                  float* __restrict__ out) {
    int d = blockIdx.y;
    int m0 = blockIdx.x * ROWS;
    int tid = threadIdx.x;
    int lane = tid & 63, wv = tid >> 6;
    int cg = tid & 31, rg = tid >> 5;

    __shared__ float A[ROWS * 256];   // [32 rows][K=256]; no pad needed (GEMM A-reads broadcast)

    float4 acc[4];
    acc[0] = acc[1] = acc[2] = acc[3] = make_float4(0.f, 0.f, 0.f, 0.f);

    for (int s = 0; s < P; ++s) {
        int pair = s * P + d;
        const float* x   = x_all + (size_t)s * NN * DD;
        const int* rsn   = rs_n_all + (size_t)pair * (MM + 1);
        const int* csn   = csn_src_all + (size_t)pair * EE;
        const float* cw  = csn_w_all + (size_t)pair * EE;
        const int* rss   = rs_s_all + (size_t)pair * (MM + 1);
        const int* css   = css_all + (size_t)pair * MM;

        // ---- gather: wave wv handles rows wv, wv+4, ... lane covers cols {2l, 2l+1}
        for (int r = wv; r < ROWS; r += 4) {
            int m = m0 + r;
            float sx = 0.f, sy = 0.f, nx = 0.f, ny = 0.f;
            if (m < MM) {
                // self-scatter sum (avg 1 row)
                int e0 = rss[m], e1 = rss[m + 1];
                for (int e = e0; e < e1; ++e) {
                    float2 v = ((const float2*)(x + (size_t)css[e] * DD))[lane];
                    sx += v.x; sy += v.y;
                }
                // weighted neigh sum (avg 8 rows), 4-wide unroll for MLP
                e0 = rsn[m]; e1 = rsn[m + 1];
                int e = e0;
                for (; e + 4 <= e1; e += 4) {
                    int j0 = csn[e], j1 = csn[e + 1], j2 = csn[e + 2], j3 = csn[e + 3];
                    float w0 = cw[e], w1 = cw[e + 1], w2 = cw[e + 2], w3 = cw[e + 3];
                    float2 v0 = ((const float2*)(x + (size_t)j0 * DD))[lane];
                    float2 v1 = ((const float2*)(x + (size_t)j1 * DD))[lane];
                    float2 v2 = ((const float2*)(x + (size_t)j2 * DD))[lane];
                    float2 v3 = ((const float2*)(x + (size_t)j3 * DD))[lane];
                    nx += w0 * v0.x + w1 * v1.x + w2 * v2.x + w3 * v3.x;
                    ny += w0 * v0.y + w1 * v1.y + w2 * v2.y + w3 * v3.y;
                }
                for (; e < e1; ++e) {
                    float w = cw[e];
                    float2 v = ((const float2*)(x + (size_t)csn[e] * DD))[lane];
                    nx += w * v.x; ny += w * v.y;
                }
            }
            ((float2*)(A + r * 256))[lane]       = make_float2(sx, sy);
            ((float2*)(A + r * 256 + 128))[lane] = make_float2(nx, ny);
        }
        __syncthreads();

        // ---- GEMM accumulate: acc[32][128] += A[32][256] @ [Ws[s]; Wn[s]]
        const float* Bhalf0 = Ws_all + (size_t)s * DD * DD;
        const float* Bhalf1 = Wn_all + (size_t)s * DD * DD;
        #pragma unroll
        for (int half = 0; half < 2; ++half) {
            const float* B = half ? Bhalf1 : Bhalf0;
            int aoff = half << 7;
            for (int k = 0; k < 128; k += 4) {
                float4 b0 = *(const float4*)(B + (size_t)(k + 0) * DD + cg * 4);
                float4 b1 = *(const float4*)(B + (size_t)(k + 1) * DD + cg * 4);
                float4 b2 = *(const float4*)(B + (size_t)(k + 2) * DD + cg * 4);
                float4 b3 = *(const float4*)(B + (size_t)(k + 3) * DD + cg * 4);
                #pragma unroll
                for (int i = 0; i < 4; ++i) {
                    float4 a = *(const float4*)(A + (rg * 4 + i) * 256 + aoff + k);
                    acc[i].x += a.x * b0.x + a.y * b1.x + a.z * b2.x + a.w * b3.x;
                    acc[i].y += a.x * b0.y + a.y * b1.y + a.z * b2.y + a.w * b3.y;
                    acc[i].z += a.x * b0.z + a.y * b1.z + a.z * b2.z + a.w * b3.z;
                    acc[i].w += a.x * b0.w + a.y * b1.w + a.z * b2.w + a.w * b3.w;
                }
            }
        }

        // ---- bias: each contributing source row brings one b[s]
        float4 bb = *(const float4*)(b_all + (size_t)s * DD + cg * 4);
        #pragma unroll
        for (int i = 0; i < 4; ++i) {
            int m = m0 + rg * 4 + i;
            if (m < MM) {
                float c = (float)(rss[m + 1] - rss[m]);
                acc[i].x += c * bb.x; acc[i].y += c * bb.y;
                acc[i].z += c * bb.z; acc[i].w += c * bb.w;
            }
        }
        __syncthreads();   // before next s overwrites A
    }

    // ---- single coalesced store
    float* outd = out + (size_t)d * MM * DD;
    #pragma unroll
    for (int i = 0; i < 4; ++i) {
        int m = m0 + rg * 4 + i;
        if (m >= MM) continue;
        *(float4*)(outd + (size_t)m * DD + cg * 4) = acc[i];
    }
}

// ---------------------------------------------------------------------------
extern "C" void kernel_launch(void* const* d_in, const int* in_sizes, int n_in,
                              void* d_out, int out_size, void* d_ws, size_t ws_size,
                              hipStream_t stream) {
    const float* x     = (const float*)d_in[0];   // [P][N][D]
    const float* Ws    = (const float*)d_in[1];   // [P][D][D]
    const float* Wn    = (const float*)d_in[2];   // [P][D][D]
    const float* b     = (const float*)d_in[3];   // [P][D]
    const int*   esrc  = (const int*)d_in[4];     // [P][P][E]
    const int*   edst  = (const int*)d_in[5];     // [P][P][E]
    const int*   merge = (const int*)d_in[6];     // [P][P][M]
    float* out = (float*)d_out;                   // [P][M][D]

    // workspace layout (ints unless noted), ~70.4 MB total:
    int* deg_orig = (int*)d_ws;                   // [16*M]
    int* cnt_n    = deg_orig + 16 * MM;           // [16*M] counts -> cursor after scan
    int* cnt_s    = cnt_n + 16 * MM;              // [16*M] counts -> cursor after scan
    int* rs_n     = cnt_s + 16 * MM;              // [16*(M+1)]
    int* rs_s     = rs_n + 16 * (MM + 1);         // [16*(M+1)]
    int* csn_src  = rs_s + 16 * (MM + 1);         // [16*E]
    float* csn_w  = (float*)(csn_src + 16 * EE);  // [16*E]
    int* css      = (int*)(csn_w + 16 * EE);      // [16*M]

    hipMemsetAsync(d_ws, 0, sizeof(int) * (size_t)16 * MM * 3, stream);  // deg+cnt_n+cnt_s

    int eblocks = (P * P * EE + 255) / 256;       // 25000
    int mblocks16 = (P * P * MM + 255) / 256;     // 3125
    k_count<<<eblocks, 256, 0, stream>>>(edst, merge, deg_orig, cnt_n);
    k_count_self<<<mblocks16, 256, 0, stream>>>(merge, cnt_s);
    k_scan<<<32, 1024, 0, stream>>>(cnt_n, rs_n, cnt_s, rs_s);
    k_fill<<<eblocks, 256, 0, stream>>>(esrc, edst, merge, deg_orig, rs_n, cnt_n, csn_src, csn_w);
    k_fill_self<<<mblocks16, 256, 0, stream>>>(merge, rs_s, cnt_s, css);

    dim3 gfused((MM + ROWS - 1) / ROWS, P);       // (1563, 4)
    k_fused<<<gfused, 256, 0, stream>>>(x, Ws, Wn, b, rs_n, csn_src, csn_w, rs_s, css, out);
}